// Round 13
// baseline (40.370 us; speedup 1.0000x reference)
//
#include <hip/hip_runtime.h>

constexpr int CODE_LEN = 1024;
constexpr int INFO_LEN = 512;
constexpr int BATCH    = 2048;
constexpr int ITERS    = 5;
#define CLIPV 15.0f

// f(a,b) = sign(a)*sign(b)*min(|a|,|b|) -- fully compiler-visible 3-op form:
// v_xor_b32 + v_min_f32(|a|,|b| modifiers) + v_bfi_b32 (copysign).
// Compiler-visible => DPP/permlane hazard wait-states are inserted correctly
// (R12's inline-asm fop defeated the hazard recognizer -> stale DPP reads).
__device__ __forceinline__ float fop(float a, float b) {
    unsigned s = __float_as_uint(a) ^ __float_as_uint(b);
    float m = fminf(fabsf(a), fabsf(b));
    return copysignf(m, __uint_as_float(s));
}
__device__ __forceinline__ float clipf(float x) {
    return __builtin_amdgcn_fmed3f(x, -CLIPV, CLIPV);
}

// ---------------------------------------------------------------------------
// R7-R12 scheme: position p at (wave,lane,slot) per layout group; butterflies
// between register slots (select-free). In-wave layout conversions (slot-bits
// <-> lane-bit-pairs) are IN-REGISTER lane butterflies on the VALU pipe:
//   lane bits [5:4]: v_permlane16_swap_b32 / v_permlane32_swap_b32 BUILTINS
//     (vdst odd rows <-> vsrc even rows; vdst = slot-bit=0 array).
//   lane bits [3:2]: chained-DPP partners (xor4, xor8) + cndmask (BSW).
//   lane bits [1:0]: DPP quad_perm partners (xor1, xor2) + cndmask.
// Bit-swap (slot-bit k <-> lane-bit m), P = slot-bit-k=0 array, Q = =1:
//   P' = bit_m(l) ? Q(l^m) : P;  Q' = bit_m(l) ? Q : P(l^m).
// Only the cross-wave CONV_X (slot <-> wave bits) stays in LDS (2 barriers/it).
// ---------------------------------------------------------------------------

template<int CTRL>
__device__ __forceinline__ float dppmv(float x) {
    return __int_as_float(__builtin_amdgcn_mov_dpp(__float_as_int(x), CTRL, 0xf, 0xf, true));
}
__device__ __forceinline__ float dppx1(float x) { return dppmv<0xB1>(x); }               // l^1
__device__ __forceinline__ float dppx2(float x) { return dppmv<0x4E>(x); }               // l^2
__device__ __forceinline__ float dppx4(float x) { return dppmv<0x1B>(dppmv<0x141>(x)); } // l^4
__device__ __forceinline__ float dppx8(float x) { return dppmv<0x141>(dppmv<0x140>(x)); }// l^8

typedef unsigned u32x2 __attribute__((ext_vector_type(2)));

// generic bit-swap: P/Q pair, partner via DPPFN, select by lane bit
#define BSW(P, Q, DPPFN, BIT) do { \
    float pa_ = DPPFN(P), pb_ = DPPFN(Q); \
    bool c_ = (l6 & (BIT)) != 0; \
    P = c_ ? pb_ : P;  Q = c_ ? Q : pa_; } while(0)

#if __has_builtin(__builtin_amdgcn_permlane16_swap)
#define PL16(P, Q) do { \
    u32x2 r_ = __builtin_amdgcn_permlane16_swap(__float_as_uint(P), __float_as_uint(Q), false, false); \
    P = __uint_as_float(r_[0]); Q = __uint_as_float(r_[1]); } while(0)
#else
__device__ __forceinline__ float swzx16(float x) {   // partner l^16 via ds_swizzle
    return __int_as_float(__builtin_amdgcn_ds_swizzle(__float_as_int(x), 0x401F));
}
#define PL16(P, Q) BSW(P, Q, swzx16, 16)
#endif

#define PL32(P, Q) do { \
    u32x2 r_ = __builtin_amdgcn_permlane32_swap(__float_as_uint(P), __float_as_uint(Q), false, false); \
    P = __uint_as_float(r_[0]); Q = __uint_as_float(r_[1]); } while(0)

// beta=4: slot0<->lane4, slot1<->lane5
#define CONV_R4(S) do { \
    PL16((S)[0], (S)[1]); PL16((S)[2], (S)[3]); \
    PL32((S)[0], (S)[2]); PL32((S)[1], (S)[3]); } while(0)
// beta=2: slot0<->lane2 (xor4), slot1<->lane3 (xor8)
#define CONV_R2(S) do { \
    BSW((S)[0], (S)[1], dppx4, 4);  BSW((S)[2], (S)[3], dppx4, 4); \
    BSW((S)[0], (S)[2], dppx8, 8);  BSW((S)[1], (S)[3], dppx8, 8); } while(0)
// beta=0: slot0<->lane0 (xor1), slot1<->lane1 (xor2)
#define CONV_R0(S) do { \
    BSW((S)[0], (S)[1], dppx1, 1);  BSW((S)[2], (S)[3], dppx1, 1); \
    BSW((S)[0], (S)[2], dppx2, 2);  BSW((S)[1], (S)[3], dppx2, 2); } while(0)

#define RSTEP0(A, B) do { \
    float bu0=(B)[0], bl0=(B)[1], bu1=(B)[2], bl1=(B)[3]; \
    (B)[0]=fop((A)[0], bl0+(A)[1]); \
    (B)[1]=clipf(fop((A)[0], bu0)+(A)[1]); \
    (B)[2]=fop((A)[2], bl1+(A)[3]); \
    (B)[3]=clipf(fop((A)[2], bu1)+(A)[3]); } while(0)
#define RSTEP1(A, B) do { \
    float bu0=(B)[0], bl0=(B)[2], bu1=(B)[1], bl1=(B)[3]; \
    (B)[0]=fop((A)[0], bl0+(A)[2]); \
    (B)[2]=clipf(fop((A)[0], bu0)+(A)[2]); \
    (B)[1]=fop((A)[1], bl1+(A)[3]); \
    (B)[3]=clipf(fop((A)[1], bu1)+(A)[3]); } while(0)
#define LSTEP0(A, B) do { \
    float au0=(A)[0], al0=(A)[1], au1=(A)[2], al1=(A)[3]; \
    (A)[0]=fop((B)[0], (B)[1]+al0); \
    (A)[1]=clipf(fop(au0, (B)[0])+(B)[1]); \
    (A)[2]=fop((B)[2], (B)[3]+al1); \
    (A)[3]=clipf(fop(au1, (B)[2])+(B)[3]); } while(0)
#define LSTEP1(A, B) do { \
    float au0=(A)[0], al0=(A)[2], au1=(A)[1], al1=(A)[3]; \
    (A)[0]=fop((B)[0], (B)[2]+al0); \
    (A)[2]=clipf(fop(au0, (B)[0])+(B)[2]); \
    (A)[1]=fop((B)[1], (B)[3]+al1); \
    (A)[3]=clipf(fop(au1, (B)[1])+(B)[3]); } while(0)
// stage-9 left step: B = rx (UNclipped) -> keep u-clip
#define LSTEP1C(A, B) do { \
    float au0=(A)[0], al0=(A)[2], au1=(A)[1], al1=(A)[3]; \
    (A)[0]=clipf(fop((B)[0], (B)[2]+al0)); \
    (A)[2]=clipf(fop(au0, (B)[0])+(B)[2]); \
    (A)[1]=clipf(fop((B)[1], (B)[3]+al1)); \
    (A)[3]=clipf(fop(au1, (B)[1])+(B)[3]); } while(0)
// iteration-0 right steps (l == 0): u' = fop(r_u, r_l), l' = r_l
#define RSTEP0Z(A, B) do { \
    (B)[0]=fop((A)[0], (A)[1]); (B)[1]=(A)[1]; \
    (B)[2]=fop((A)[2], (A)[3]); (B)[3]=(A)[3]; } while(0)
#define RSTEP1Z(A, B) do { \
    (B)[0]=fop((A)[0], (A)[2]); (B)[2]=(A)[2]; \
    (B)[1]=fop((A)[1], (A)[3]); (B)[3]=(A)[3]; } while(0)

// LDS-only barrier: no vmcnt drain (emit stores stay in flight).
#define XBAR() do { \
    asm volatile("s_waitcnt lgkmcnt(0)" ::: "memory"); \
    __builtin_amdgcn_s_barrier(); \
    __builtin_amdgcn_sched_barrier(0); } while(0)

// cross-wave conversion (slot <-> wave bits): tuple-permute by m to kill
// read-bank conflicts, write b128, barrier, strided read. XB0/XB1 alternate.
#define CONV_X(arr, XBUF) do { \
    float T0_ = mb0 ? (arr)[1] : (arr)[0]; \
    float T1_ = mb0 ? (arr)[0] : (arr)[1]; \
    float T2_ = mb0 ? (arr)[3] : (arr)[2]; \
    float T3_ = mb0 ? (arr)[2] : (arr)[3]; \
    float U0_ = mb1 ? T2_ : T0_; \
    float U1_ = mb1 ? T3_ : T1_; \
    float U2_ = mb1 ? T0_ : T2_; \
    float U3_ = mb1 ? T1_ : T3_; \
    *(float4*)&(XBUF)[wX] = make_float4(U0_, U1_, U2_, U3_); \
    XBAR(); \
    const float* xp_ = &(XBUF)[rX]; \
    float c0_ = xp_[0], c1_ = xp_[256], c2_ = xp_[512], c3_ = xp_[768]; \
    (arr)[0]=c0_; (arr)[1]=c1_; (arr)[2]=c2_; (arr)[3]=c3_; } while(0)

__global__ __launch_bounds__(256, 4) void polar_bp_r13(const float* __restrict__ rx,
                                                       const int* __restrict__ info,
                                                       float* __restrict__ out) {
    __shared__ int   RK[CODE_LEN];    // rank table in L0 flat order (init only)
    __shared__ float XB0[CODE_LEN];   // cross-wave buffers (alternating)
    __shared__ float XB1[CODE_LEN];

    const int t = threadIdx.x;
    const int b = blockIdx.x;

    // RK[L0-flat] = rank or -1. flat(p) = p10 | p76<<2 | p54<<4 | p32<<6 | p98<<8
    *(int4*)&RK[t * 4] = make_int4(-1, -1, -1, -1);
    __syncthreads();
#pragma unroll
    for (int k = 0; k < 2; ++k) {
        int kk = t + 256 * k;
        int p  = info[kk];
        int fl = (p & 3) | (((p >> 6) & 3) << 2) | (((p >> 4) & 3) << 4)
               | (((p >> 2) & 3) << 6) | (((p >> 8) & 3) << 8);
        RK[fl] = kk;
    }
    __syncthreads();

    const int l6 = t & 63;
    const int w  = t >> 6;
    // CONV_X constants: word(w',l6',s') = 4*l6' + 256*w' + (s' ^ ((l6'>>3)&3))
    const int  mX  = (l6 >> 3) & 3;
    const bool mb0 = (l6 & 8)  != 0;
    const bool mb1 = (l6 & 16) != 0;
    const int  wX  = 4 * l6 + 256 * w;
    const int  rX  = 4 * l6 + (w ^ mX);

    // ---- per-thread constants: ranks + frozen vector ----
    const int4 rkv = *(const int4*)&RK[t * 4];
    float fr[4];
    fr[0] = rkv.x < 0 ? CLIPV : 0.f;  fr[1] = rkv.y < 0 ? CLIPV : 0.f;
    fr[2] = rkv.z < 0 ? CLIPV : 0.f;  fr[3] = rkv.w < 0 ? CLIPV : 0.f;

    float S[10][4];
    // rx -> S[9] in L4 order: p = e*256 + t76*64 + t10*16 + t32*4 + t54
    {
        const float* rxb = rx + (size_t)b * CODE_LEN
                         + ((t >> 6) & 3) * 64 + (t & 3) * 16
                         + ((t >> 2) & 3) * 4 + ((t >> 4) & 3);
        S[9][0] = rxb[0];   S[9][1] = rxb[256];
        S[9][2] = rxb[512]; S[9][3] = rxb[768];
    }

    // ===== iteration-0 RIGHT pass, peeled: all left arrays are zero =====
    RSTEP0Z(fr, S[0]);
    RSTEP1Z(S[0], S[1]);
    CONV_R4(S[1]);             // C01  L0->L1 (in-register)
    RSTEP0Z(S[1], S[2]);
    RSTEP1Z(S[2], S[3]);
    CONV_R2(S[3]);             // C12  L1->L2 (in-register)
    RSTEP0Z(S[3], S[4]);
    RSTEP1Z(S[4], S[5]);
    CONV_R0(S[5]);             // C23  L2->L3 (in-register)
    RSTEP0Z(S[5], S[6]);
    RSTEP1Z(S[6], S[7]);
    CONV_X(S[7], XB0);         // C34  L3->L4 (LDS, barrier)
    RSTEP0Z(S[7], S[8]);       // s8 (right stage 9 output unused)

    float v0, v1, v2, v3;
    float* ob = out + (size_t)b * INFO_LEN;
    const size_t obstride = (size_t)BATCH * INFO_LEN;

#pragma unroll 1
    for (int it = 0; it < ITERS; ++it) {
        // ===================== LEFT pass (s = 9..0) ======================
        LSTEP1C(S[8], S[9]);       // s9: l = rx (unclipped) -> keep u-clip
        LSTEP0(S[7], S[8]);        // s8
        CONV_X(S[7], XB1);         // C43  L4->L3 (LDS, barrier)
        LSTEP1(S[6], S[7]);        // s7
        LSTEP0(S[5], S[6]);        // s6
        CONV_R0(S[5]);             // C32  L3->L2
        LSTEP1(S[4], S[5]);        // s5
        LSTEP0(S[3], S[4]);        // s4
        CONV_R2(S[3]);             // C21  L2->L1
        LSTEP1(S[2], S[3]);        // s3
        LSTEP0(S[1], S[2]);        // s2
        CONV_R4(S[1]);             // C10  L1->L0
        LSTEP1(S[0], S[1]);        // s1 -> S[0] = left[1]
        // s0: emit left[0] at info positions (right[0] = 0 there), L0 order
        v0 = fop(S[0][0], S[0][1] + fr[1]);
        v1 = clipf(fop(fr[0], S[0][0]) + S[0][1]);
        v2 = fop(S[0][2], S[0][3] + fr[3]);
        v3 = clipf(fop(fr[2], S[0][2]) + S[0][3]);
        if (rkv.x >= 0) ob[rkv.x] = v0;
        if (rkv.y >= 0) ob[rkv.y] = v1;
        if (rkv.z >= 0) ob[rkv.z] = v2;
        if (rkv.w >= 0) ob[rkv.w] = v3;
        ob += obstride;
        // ===================== RIGHT pass (s = 0..8) =====================
        if (it != ITERS - 1) {
            RSTEP0(fr, S[0]);
            RSTEP1(S[0], S[1]);
            CONV_R4(S[1]);             // C01
            RSTEP0(S[1], S[2]);
            RSTEP1(S[2], S[3]);
            CONV_R2(S[3]);             // C12
            RSTEP0(S[3], S[4]);
            RSTEP1(S[4], S[5]);
            CONV_R0(S[5]);             // C23
            RSTEP0(S[5], S[6]);
            RSTEP1(S[6], S[7]);
            CONV_X(S[7], XB0);         // C34 (LDS, barrier)
            RSTEP0(S[7], S[8]);
        }
    }
    // duplicate row: out[ITERS] = out[ITERS-1]
    if (rkv.x >= 0) ob[rkv.x] = v0;
    if (rkv.y >= 0) ob[rkv.y] = v1;
    if (rkv.z >= 0) ob[rkv.z] = v2;
    if (rkv.w >= 0) ob[rkv.w] = v3;
}

extern "C" void kernel_launch(void* const* d_in, const int* in_sizes, int n_in,
                              void* d_out, int out_size, void* d_ws, size_t ws_size,
                              hipStream_t stream) {
    const float* rx   = (const float*)d_in[0];
    const int*   info = (const int*)d_in[1];
    float*       outp = (float*)d_out;
    polar_bp_r13<<<dim3(BATCH), dim3(256), 0, stream>>>(rx, info, outp);
}

// Round 14
// 36.600 us; speedup vs baseline: 1.1030x; 1.1030x over previous
//
#include <hip/hip_runtime.h>

constexpr int CODE_LEN = 1024;
constexpr int INFO_LEN = 512;
constexpr int BATCH    = 2048;
constexpr int ITERS    = 5;
#define CLIPV 15.0f

// f(a,b) = sign(a)*sign(b)*min(|a|,|b|) -- compiler-visible 3-op form
// (v_xor + v_min|a||b| + v_bfi/copysign). Keeps the DPP/permlane hazard
// recognizer effective (R12 lesson: asm-fop + permlane = stale reads).
__device__ __forceinline__ float fop(float a, float b) {
    unsigned s = __float_as_uint(a) ^ __float_as_uint(b);
    float m = fminf(fabsf(a), fabsf(b));
    return copysignf(m, __uint_as_float(s));
}
__device__ __forceinline__ float clipf(float x) {
    return __builtin_amdgcn_fmed3f(x, -CLIPV, CLIPV);
}

// ---------------------------------------------------------------------------
// Layout scheme (R7+): position p at (wave,lane,slot) per group; butterflies
// between register slots (select-free). Conversions:
//   C01/C10 (slot <-> lane bits [5:4]): IN-REGISTER via v_permlane16_swap /
//     v_permlane32_swap builtins (4 inst, R13-verified) -- R14 keeps these.
//   C12/C21, C23/C32 (lane bits [3:2], [1:0]): LDS CONV_W (R9 form) -- the
//     R13 DPP-chain versions regressed 25%, reverted.
//   C34/C43 (slot <-> wave bits): LDS CONV_X, 1 barrier each (2/iter).
// ---------------------------------------------------------------------------

typedef unsigned u32x2 __attribute__((ext_vector_type(2)));

#define PL16(P, Q) do { \
    u32x2 r_ = __builtin_amdgcn_permlane16_swap(__float_as_uint(P), __float_as_uint(Q), false, false); \
    P = __uint_as_float(r_[0]); Q = __uint_as_float(r_[1]); } while(0)
#define PL32(P, Q) do { \
    u32x2 r_ = __builtin_amdgcn_permlane32_swap(__float_as_uint(P), __float_as_uint(Q), false, false); \
    P = __uint_as_float(r_[0]); Q = __uint_as_float(r_[1]); } while(0)

// beta=4: slot0<->lane4, slot1<->lane5 (in-register, 4 instructions)
#define CONV_R4(S) do { \
    PL16((S)[0], (S)[1]); PL16((S)[2], (S)[3]); \
    PL32((S)[0], (S)[2]); PL32((S)[1], (S)[3]); } while(0)

#define RSTEP0(A, B) do { \
    float bu0=(B)[0], bl0=(B)[1], bu1=(B)[2], bl1=(B)[3]; \
    (B)[0]=fop((A)[0], bl0+(A)[1]); \
    (B)[1]=clipf(fop((A)[0], bu0)+(A)[1]); \
    (B)[2]=fop((A)[2], bl1+(A)[3]); \
    (B)[3]=clipf(fop((A)[2], bu1)+(A)[3]); } while(0)
#define RSTEP1(A, B) do { \
    float bu0=(B)[0], bl0=(B)[2], bu1=(B)[1], bl1=(B)[3]; \
    (B)[0]=fop((A)[0], bl0+(A)[2]); \
    (B)[2]=clipf(fop((A)[0], bu0)+(A)[2]); \
    (B)[1]=fop((A)[1], bl1+(A)[3]); \
    (B)[3]=clipf(fop((A)[1], bu1)+(A)[3]); } while(0)
#define LSTEP0(A, B) do { \
    float au0=(A)[0], al0=(A)[1], au1=(A)[2], al1=(A)[3]; \
    (A)[0]=fop((B)[0], (B)[1]+al0); \
    (A)[1]=clipf(fop(au0, (B)[0])+(B)[1]); \
    (A)[2]=fop((B)[2], (B)[3]+al1); \
    (A)[3]=clipf(fop(au1, (B)[2])+(B)[3]); } while(0)
#define LSTEP1(A, B) do { \
    float au0=(A)[0], al0=(A)[2], au1=(A)[1], al1=(A)[3]; \
    (A)[0]=fop((B)[0], (B)[2]+al0); \
    (A)[2]=clipf(fop(au0, (B)[0])+(B)[2]); \
    (A)[1]=fop((B)[1], (B)[3]+al1); \
    (A)[3]=clipf(fop(au1, (B)[1])+(B)[3]); } while(0)
// stage-9 left step: B = rx (UNclipped) -> keep u-clip
#define LSTEP1C(A, B) do { \
    float au0=(A)[0], al0=(A)[2], au1=(A)[1], al1=(A)[3]; \
    (A)[0]=clipf(fop((B)[0], (B)[2]+al0)); \
    (A)[2]=clipf(fop(au0, (B)[0])+(B)[2]); \
    (A)[1]=clipf(fop((B)[1], (B)[3]+al1)); \
    (A)[3]=clipf(fop(au1, (B)[1])+(B)[3]); } while(0)
// iteration-0 right steps (l == 0): u' = fop(r_u, r_l), l' = r_l
#define RSTEP0Z(A, B) do { \
    (B)[0]=fop((A)[0], (A)[1]); (B)[1]=(A)[1]; \
    (B)[2]=fop((A)[2], (A)[3]); (B)[3]=(A)[3]; } while(0)
#define RSTEP1Z(A, B) do { \
    (B)[0]=fop((A)[0], (A)[2]); (B)[2]=(A)[2]; \
    (B)[1]=fop((A)[1], (A)[3]); (B)[3]=(A)[3]; } while(0)

// LDS-only barrier: no vmcnt drain (emit stores stay in flight).
#define XBAR() do { \
    asm volatile("s_waitcnt lgkmcnt(0)" ::: "memory"); \
    __builtin_amdgcn_s_barrier(); \
    __builtin_amdgcn_sched_barrier(0); } while(0)

// in-wave conversion via LDS (R9 form): write b128 at pi(l6), strided reads
#define CONV_W(arr, WBASE, RBASE) do { \
    *(float4*)&WB[WBASE] = make_float4((arr)[0], (arr)[1], (arr)[2], (arr)[3]); \
    const float* rp_ = &WB[RBASE]; \
    float c0_ = rp_[0], c1_ = rp_[64], c2_ = rp_[128], c3_ = rp_[192]; \
    (arr)[0]=c0_; (arr)[1]=c1_; (arr)[2]=c2_; (arr)[3]=c3_; } while(0)

// cross-wave conversion (slot <-> wave bits): tuple-permute by m kills
// read-bank conflicts; write b128, barrier, strided read. XB0/XB1 alternate.
#define CONV_X(arr, XBUF) do { \
    float T0_ = mb0 ? (arr)[1] : (arr)[0]; \
    float T1_ = mb0 ? (arr)[0] : (arr)[1]; \
    float T2_ = mb0 ? (arr)[3] : (arr)[2]; \
    float T3_ = mb0 ? (arr)[2] : (arr)[3]; \
    float U0_ = mb1 ? T2_ : T0_; \
    float U1_ = mb1 ? T3_ : T1_; \
    float U2_ = mb1 ? T0_ : T2_; \
    float U3_ = mb1 ? T1_ : T3_; \
    *(float4*)&(XBUF)[wX] = make_float4(U0_, U1_, U2_, U3_); \
    XBAR(); \
    const float* xp_ = &(XBUF)[rX]; \
    float c0_ = xp_[0], c1_ = xp_[256], c2_ = xp_[512], c3_ = xp_[768]; \
    (arr)[0]=c0_; (arr)[1]=c1_; (arr)[2]=c2_; (arr)[3]=c3_; } while(0)

__global__ __launch_bounds__(256, 4) void polar_bp_r14(const float* __restrict__ rx,
                                                       const int* __restrict__ info,
                                                       float* __restrict__ out) {
    __shared__ int   RK[CODE_LEN];    // rank table in L0 flat order (init only)
    __shared__ float WB[CODE_LEN];    // per-wave conversion scratch (4x256)
    __shared__ float XB0[CODE_LEN];   // cross-wave buffers (alternating)
    __shared__ float XB1[CODE_LEN];

    const int t = threadIdx.x;
    const int b = blockIdx.x;

    // RK[L0-flat] = rank or -1. flat(p) = p10 | p76<<2 | p54<<4 | p32<<6 | p98<<8
    *(int4*)&RK[t * 4] = make_int4(-1, -1, -1, -1);
    __syncthreads();
#pragma unroll
    for (int k = 0; k < 2; ++k) {
        int kk = t + 256 * k;
        int p  = info[kk];
        int fl = (p & 3) | (((p >> 6) & 3) << 2) | (((p >> 4) & 3) << 4)
               | (((p >> 2) & 3) << 6) | (((p >> 8) & 3) << 8);
        RK[fl] = kk;
    }
    __syncthreads();

    // ---- precomputed LDS dword offsets (iteration-invariant) ----
    const int l6 = t & 63;
    const int w  = t >> 6;
    const int wbase = w * 256;
    // beta=2: pi(g) = (g&3) | ((g>>4)&3)<<2 | ((g>>2)&3)<<4
    const int wW2 = wbase + 4 * ((l6 & 3) | (((l6 >> 4) & 3) << 2) | (((l6 >> 2) & 3) << 4));
    const int rW2 = wbase + 4 * ((l6 & 3) | (((l6 >> 4) & 3) << 2)) + ((l6 >> 2) & 3);
    // beta=0: pi(g) = ((g>>2)&15) | (g&3)<<4
    const int wW0 = wbase + 4 * (((l6 >> 2) & 15) | ((l6 & 3) << 4));
    const int rW0 = wbase + 4 * ((l6 >> 2) & 15) + (l6 & 3);
    // CONV_X: word(w',l6',s') = 4*l6' + 256*w' + (s' ^ ((l6'>>3)&3))
    const int  mX  = (l6 >> 3) & 3;
    const bool mb0 = (l6 & 8)  != 0;
    const bool mb1 = (l6 & 16) != 0;
    const int  wX  = 4 * l6 + 256 * w;
    const int  rX  = 4 * l6 + (w ^ mX);

    // ---- per-thread constants: ranks + frozen vector ----
    const int4 rkv = *(const int4*)&RK[t * 4];
    float fr[4];
    fr[0] = rkv.x < 0 ? CLIPV : 0.f;  fr[1] = rkv.y < 0 ? CLIPV : 0.f;
    fr[2] = rkv.z < 0 ? CLIPV : 0.f;  fr[3] = rkv.w < 0 ? CLIPV : 0.f;

    float S[10][4];
    // rx -> S[9] in L4 order: p = e*256 + t76*64 + t10*16 + t32*4 + t54
    {
        const float* rxb = rx + (size_t)b * CODE_LEN
                         + ((t >> 6) & 3) * 64 + (t & 3) * 16
                         + ((t >> 2) & 3) * 4 + ((t >> 4) & 3);
        S[9][0] = rxb[0];   S[9][1] = rxb[256];
        S[9][2] = rxb[512]; S[9][3] = rxb[768];
    }

    // ===== iteration-0 RIGHT pass, peeled: all left arrays are zero =====
    RSTEP0Z(fr, S[0]);
    RSTEP1Z(S[0], S[1]);
    CONV_R4(S[1]);             // C01  L0->L1 (in-register permlane)
    RSTEP0Z(S[1], S[2]);
    RSTEP1Z(S[2], S[3]);
    CONV_W(S[3], wW2, rW2);    // C12  L1->L2 (LDS)
    RSTEP0Z(S[3], S[4]);
    RSTEP1Z(S[4], S[5]);
    CONV_W(S[5], wW0, rW0);    // C23  L2->L3 (LDS)
    RSTEP0Z(S[5], S[6]);
    RSTEP1Z(S[6], S[7]);
    CONV_X(S[7], XB0);         // C34  L3->L4 (LDS, barrier)
    RSTEP0Z(S[7], S[8]);       // s8 (right stage 9 output unused)

    float v0, v1, v2, v3;
    float* ob = out + (size_t)b * INFO_LEN;
    const size_t obstride = (size_t)BATCH * INFO_LEN;

#pragma unroll 1
    for (int it = 0; it < ITERS; ++it) {
        // ===================== LEFT pass (s = 9..0) ======================
        LSTEP1C(S[8], S[9]);       // s9: l = rx (unclipped) -> keep u-clip
        LSTEP0(S[7], S[8]);        // s8
        CONV_X(S[7], XB1);         // C43  L4->L3 (LDS, barrier)
        LSTEP1(S[6], S[7]);        // s7
        LSTEP0(S[5], S[6]);        // s6
        CONV_W(S[5], wW0, rW0);    // C32  L3->L2 (LDS)
        LSTEP1(S[4], S[5]);        // s5
        LSTEP0(S[3], S[4]);        // s4
        CONV_W(S[3], wW2, rW2);    // C21  L2->L1 (LDS)
        LSTEP1(S[2], S[3]);        // s3
        LSTEP0(S[1], S[2]);        // s2
        CONV_R4(S[1]);             // C10  L1->L0 (in-register permlane)
        LSTEP1(S[0], S[1]);        // s1 -> S[0] = left[1]
        // s0: emit left[0] at info positions (right[0] = 0 there), L0 order
        v0 = fop(S[0][0], S[0][1] + fr[1]);
        v1 = clipf(fop(fr[0], S[0][0]) + S[0][1]);
        v2 = fop(S[0][2], S[0][3] + fr[3]);
        v3 = clipf(fop(fr[2], S[0][2]) + S[0][3]);
        if (rkv.x >= 0) ob[rkv.x] = v0;
        if (rkv.y >= 0) ob[rkv.y] = v1;
        if (rkv.z >= 0) ob[rkv.z] = v2;
        if (rkv.w >= 0) ob[rkv.w] = v3;
        ob += obstride;
        // ===================== RIGHT pass (s = 0..8) =====================
        if (it != ITERS - 1) {
            RSTEP0(fr, S[0]);
            RSTEP1(S[0], S[1]);
            CONV_R4(S[1]);             // C01 (permlane)
            RSTEP0(S[1], S[2]);
            RSTEP1(S[2], S[3]);
            CONV_W(S[3], wW2, rW2);    // C12
            RSTEP0(S[3], S[4]);
            RSTEP1(S[4], S[5]);
            CONV_W(S[5], wW0, rW0);    // C23
            RSTEP0(S[5], S[6]);
            RSTEP1(S[6], S[7]);
            CONV_X(S[7], XB0);         // C34 (barrier)
            RSTEP0(S[7], S[8]);
        }
    }
    // duplicate row: out[ITERS] = out[ITERS-1]
    if (rkv.x >= 0) ob[rkv.x] = v0;
    if (rkv.y >= 0) ob[rkv.y] = v1;
    if (rkv.z >= 0) ob[rkv.z] = v2;
    if (rkv.w >= 0) ob[rkv.w] = v3;
}

extern "C" void kernel_launch(void* const* d_in, const int* in_sizes, int n_in,
                              void* d_out, int out_size, void* d_ws, size_t ws_size,
                              hipStream_t stream) {
    const float* rx   = (const float*)d_in[0];
    const int*   info = (const int*)d_in[1];
    float*       outp = (float*)d_out;
    polar_bp_r14<<<dim3(BATCH), dim3(256), 0, stream>>>(rx, info, outp);
}

// Round 15
// 35.566 us; speedup vs baseline: 1.1351x; 1.0291x over previous
//
#include <hip/hip_runtime.h>

constexpr int CODE_LEN = 1024;
constexpr int INFO_LEN = 512;
constexpr int BATCH    = 2048;
constexpr int ITERS    = 5;
#define CLIPV 15.0f

// f(a,b) = sign(a)*sign(b)*min(|a|,|b|) -- 3-inst asm (R9-proven with LDS-only
// data movement; no DPP/permlane in this kernel so no hazard-recognizer hole).
__device__ __forceinline__ float fop(float a, float b) {
    unsigned x; float m, r;
    asm("v_xor_b32 %0, %1, %2" : "=v"(x) : "v"(a), "v"(b));
    asm("v_min_f32 %0, |%1|, |%2|" : "=v"(m) : "v"(a), "v"(b));
    asm("v_and_or_b32 %0, %1, %2, %3" : "=v"(r) : "v"(x), "s"(0x80000000u), "v"(m));
    return r;
}
__device__ __forceinline__ float clipf(float x) {
    return __builtin_amdgcn_fmed3f(x, -CLIPV, CLIPV);
}

// ---------------------------------------------------------------------------
// R15: 8 slots/thread, 2 waves/codeword (block = 2 codewords).
// Layouts (p = 10-bit position; lane l6, wave w1 = p9 always):
//   L0: slot=p[2:0], lane=p[8:3]            (stages 0,1,2; frozen/RK; emit)
//   L1: slot=p[5:3], lane=p[8:6]||p[2:0]    (stages 3,4,5)
//   L2: slot=p[8:6], lane=p[5:3]||p[2:0]    (stages 6,7,8; rx; stage 9)
// All stages are select-free slot-bit butterflies. Conversions (C01: swap
// slot<->lane[2:0]; C12: swap slot<->lane[5:3]) go through per-wave LDS with
// layout word = 8*pi(lane)+slot, pi(l)=l^(l>>3):
//   write = 2x b128 at 8*pi(l6); reads = single-XOR addrs:
//   C01/C10: DA ^ (8j),  DA = 512g + 72a + b   (a=l6>>3, b=l6&7)
//   C12/C21: EB ^ (72j), EB = 512g + 8b + a    (verified 2-lanes/bank)
// Stage 9 = direct cross-wave exchange (1 value/elem pre-combined): upper
// sends fop(r,l), lower sends l+r; ONE barrier per iteration (right pass has
// none). Exchange buffers XE0/XE1 alternate by parity (WAR barrier-separated).
// Storage: S[s]=left[s+1] before right pass, right[s+1] after; left pass
// rewrites S[s-1]=left[s]; S[9]=rx read-only. Clip dropping as R9 (u-outputs
// with clipped min-arg skip clip; stage-9 outputs keep clip: rx unclipped).
// ---------------------------------------------------------------------------

#define RP(A, B, U, L) { float bu_=(B)[U]; \
    (B)[U]=fop((A)[U], (B)[L]+(A)[L]); \
    (B)[L]=clipf(fop((A)[U], bu_)+(A)[L]); }
#define RSTEP_B0(A, B) { RP(A,B,0,1) RP(A,B,2,3) RP(A,B,4,5) RP(A,B,6,7) }
#define RSTEP_B1(A, B) { RP(A,B,0,2) RP(A,B,1,3) RP(A,B,4,6) RP(A,B,5,7) }
#define RSTEP_B2(A, B) { RP(A,B,0,4) RP(A,B,1,5) RP(A,B,2,6) RP(A,B,3,7) }

#define LP(A, B, U, L) { float au_=(A)[U]; \
    (A)[U]=fop((B)[U], (B)[L]+(A)[L]); \
    (A)[L]=clipf(fop(au_, (B)[U])+(B)[L]); }
#define LSTEP_B0(A, B) { LP(A,B,0,1) LP(A,B,2,3) LP(A,B,4,5) LP(A,B,6,7) }
#define LSTEP_B1(A, B) { LP(A,B,0,2) LP(A,B,1,3) LP(A,B,4,6) LP(A,B,5,7) }
#define LSTEP_B2(A, B) { LP(A,B,0,4) LP(A,B,1,5) LP(A,B,2,6) LP(A,B,3,7) }

// iteration-0 right steps (all left arrays zero): u'=fop(r_u,r_l), l'=r_l
#define ZP(A, B, U, L) { (B)[U]=fop((A)[U],(A)[L]); (B)[L]=(A)[L]; }
#define ZSTEP_B0(A, B) { ZP(A,B,0,1) ZP(A,B,2,3) ZP(A,B,4,5) ZP(A,B,6,7) }
#define ZSTEP_B1(A, B) { ZP(A,B,0,2) ZP(A,B,1,3) ZP(A,B,4,6) ZP(A,B,5,7) }
#define ZSTEP_B2(A, B) { ZP(A,B,0,4) ZP(A,B,1,5) ZP(A,B,2,6) ZP(A,B,3,7) }

#define LDW(X) (*(const float*)((const char*)WB + (X)))

// in-wave conversion: 2x b128 write at 8*pi(l6), 8 XOR-addressed b32 reads.
// BASE4 = byte base, STR4 = byte XOR stride (32 for C01/C10, 288 for C12/C21).
#define CONV(S_, BASE4, STR4) { \
    *(float4*)&WB[wbW]     = make_float4((S_)[0], (S_)[1], (S_)[2], (S_)[3]); \
    *(float4*)&WB[wbW + 4] = make_float4((S_)[4], (S_)[5], (S_)[6], (S_)[7]); \
    float n0_=LDW((BASE4)^(0*(STR4))), n1_=LDW((BASE4)^(1*(STR4))); \
    float n2_=LDW((BASE4)^(2*(STR4))), n3_=LDW((BASE4)^(3*(STR4))); \
    float n4_=LDW((BASE4)^(4*(STR4))), n5_=LDW((BASE4)^(5*(STR4))); \
    float n6_=LDW((BASE4)^(6*(STR4))), n7_=LDW((BASE4)^(7*(STR4))); \
    (S_)[0]=n0_; (S_)[1]=n1_; (S_)[2]=n2_; (S_)[3]=n3_; \
    (S_)[4]=n4_; (S_)[5]=n5_; (S_)[6]=n6_; (S_)[7]=n7_; }

// LDS-only barrier (no vmcnt drain; emit stores stay in flight)
#define XBAR() do { \
    asm volatile("s_waitcnt lgkmcnt(0)" ::: "memory"); \
    __builtin_amdgcn_s_barrier(); \
    __builtin_amdgcn_sched_barrier(0); } while(0)

__global__ __launch_bounds__(256, 2) void polar_bp_r15(const float* __restrict__ rx,
                                                       const int* __restrict__ info,
                                                       float* __restrict__ out) {
    __shared__ int   RK2[CODE_LEN];   // natural order: RK2[p] = rank or -1
    __shared__ float WB[2048];        // per-wave conversion scratch (512 each)
    __shared__ float XE0[2048];       // stage-9 exchange buffers (alternating)
    __shared__ float XE1[2048];

    const int t = threadIdx.x;

    *(int4*)&RK2[4 * t] = make_int4(-1, -1, -1, -1);
    __syncthreads();
#pragma unroll
    for (int k = 0; k < 2; ++k) { int kk = t + 256 * k; RK2[info[kk]] = kk; }
    __syncthreads();

    const int l6 = t & 63;
    const int g  = t >> 6;            // wave in block (0..3)
    const int w1 = g & 1;             // wave in codeword = p9
    const int cw = blockIdx.x * 2 + (t >> 7);
    const int a  = l6 >> 3, b = l6 & 7;

    // conversion addressing (word / byte, iteration-invariant)
    const int wbW = 512 * g + 8 * (l6 ^ a);        // b128 write base (words)
    const int DA4 = 4 * (512 * g + 72 * a + b);    // C01/C10 read base (bytes)
    const int EB4 = 4 * (512 * g + 8 * b + a);     // C12/C21 read base (bytes)
    // stage-9 exchange (words): own region 512g, partner wave g^1, stride 64/slot
    const int exW = 512 * g + l6;
    const int exR = 512 * (g ^ 1) + l6;

    // frozen vector + (ranks reloaded at emit)
    const int rkb = w1 * 512 + l6 * 8;             // == p base for this thread
    float fr[8];
    {
        int4 r0 = *(const int4*)&RK2[rkb];
        int4 r1 = *(const int4*)&RK2[rkb + 4];
        fr[0] = r0.x < 0 ? CLIPV : 0.f;  fr[1] = r0.y < 0 ? CLIPV : 0.f;
        fr[2] = r0.z < 0 ? CLIPV : 0.f;  fr[3] = r0.w < 0 ? CLIPV : 0.f;
        fr[4] = r1.x < 0 ? CLIPV : 0.f;  fr[5] = r1.y < 0 ? CLIPV : 0.f;
        fr[6] = r1.z < 0 ? CLIPV : 0.f;  fr[7] = r1.w < 0 ? CLIPV : 0.f;
    }

    float S[10][8];
    // rx -> S[9] in L2 order: p = (w1<<9) | (slot<<6) | l6
    {
        const float* rxp = rx + (size_t)cw * CODE_LEN + w1 * 512 + l6;
#pragma unroll
        for (int j = 0; j < 8; ++j) S[9][j] = rxp[64 * j];
    }

    // ===== iteration-0 RIGHT pass, peeled (left arrays all zero) =====
    ZSTEP_B0(fr,   S[0]);       // s0
    ZSTEP_B1(S[0], S[1]);       // s1
    ZSTEP_B2(S[1], S[2]);       // s2
    CONV(S[2], DA4, 32);        // C01  L0->L1
    ZSTEP_B0(S[2], S[3]);       // s3
    ZSTEP_B1(S[3], S[4]);       // s4
    ZSTEP_B2(S[4], S[5]);       // s5
    CONV(S[5], EB4, 288);       // C12  L1->L2
    ZSTEP_B0(S[5], S[6]);       // s6
    ZSTEP_B1(S[6], S[7]);       // s7
    ZSTEP_B2(S[7], S[8]);       // s8  (right stage 9 never consumed)

    float ve[8];
    float* ob = out + (size_t)cw * INFO_LEN;
    const size_t obstride = (size_t)BATCH * INFO_LEN;

#pragma unroll 1
    for (int it = 0; it < ITERS; ++it) {
        // =================== LEFT pass (s = 9..0) ====================
        {   // s9: cross-wave exchange; l = S[9] = rx (unclipped), r = S[8]
            float* XEp = (it & 1) ? XE1 : XE0;
            if (w1 == 0) {
#pragma unroll
                for (int j = 0; j < 8; ++j) XEp[exW + 64 * j] = fop(S[8][j], S[9][j]);
            } else {
#pragma unroll
                for (int j = 0; j < 8; ++j) XEp[exW + 64 * j] = S[9][j] + S[8][j];
            }
            XBAR();
            if (w1 == 0) {
#pragma unroll
                for (int j = 0; j < 8; ++j) {
                    float rc = XEp[exR + 64 * j];
                    S[8][j] = clipf(fop(S[9][j], rc));
                }
            } else {
#pragma unroll
                for (int j = 0; j < 8; ++j) {
                    float rc = XEp[exR + 64 * j];
                    S[8][j] = clipf(rc + S[9][j]);
                }
            }
        }
        LSTEP_B2(S[7], S[8]);       // s8 -> S[7] = left[8]
        LSTEP_B1(S[6], S[7]);       // s7
        LSTEP_B0(S[5], S[6]);       // s6 -> S[5] = left[6]
        CONV(S[5], EB4, 288);       // C21  L2->L1
        LSTEP_B2(S[4], S[5]);       // s5
        LSTEP_B1(S[3], S[4]);       // s4
        LSTEP_B0(S[2], S[3]);       // s3 -> S[2] = left[3]
        CONV(S[2], DA4, 32);        // C10  L1->L0
        LSTEP_B2(S[1], S[2]);       // s2
        LSTEP_B1(S[0], S[1]);       // s1 -> S[0] = left[1]
        // s0: emit left[0] at info positions (right[0] = 0 there), L0 order
        ve[0] = fop(S[0][0], S[0][1] + fr[1]);
        ve[1] = clipf(fop(fr[0], S[0][0]) + S[0][1]);
        ve[2] = fop(S[0][2], S[0][3] + fr[3]);
        ve[3] = clipf(fop(fr[2], S[0][2]) + S[0][3]);
        ve[4] = fop(S[0][4], S[0][5] + fr[5]);
        ve[5] = clipf(fop(fr[4], S[0][4]) + S[0][5]);
        ve[6] = fop(S[0][6], S[0][7] + fr[7]);
        ve[7] = clipf(fop(fr[6], S[0][6]) + S[0][7]);
        {
            int4 r0 = *(const int4*)&RK2[rkb];
            int4 r1 = *(const int4*)&RK2[rkb + 4];
            if (r0.x >= 0) ob[r0.x] = ve[0];
            if (r0.y >= 0) ob[r0.y] = ve[1];
            if (r0.z >= 0) ob[r0.z] = ve[2];
            if (r0.w >= 0) ob[r0.w] = ve[3];
            if (r1.x >= 0) ob[r1.x] = ve[4];
            if (r1.y >= 0) ob[r1.y] = ve[5];
            if (r1.z >= 0) ob[r1.z] = ve[6];
            if (r1.w >= 0) ob[r1.w] = ve[7];
        }
        ob += obstride;
        // =================== RIGHT pass (s = 0..8) ===================
        if (it != ITERS - 1) {
            RSTEP_B0(fr,   S[0]);       // s0 (r = frozen)
            RSTEP_B1(S[0], S[1]);       // s1
            RSTEP_B2(S[1], S[2]);       // s2
            CONV(S[2], DA4, 32);        // C01
            RSTEP_B0(S[2], S[3]);       // s3
            RSTEP_B1(S[3], S[4]);       // s4
            RSTEP_B2(S[4], S[5]);       // s5
            CONV(S[5], EB4, 288);       // C12
            RSTEP_B0(S[5], S[6]);       // s6
            RSTEP_B1(S[6], S[7]);       // s7
            RSTEP_B2(S[7], S[8]);       // s8
        }
    }
    // duplicate row: out[ITERS] = out[ITERS-1]
    {
        int4 r0 = *(const int4*)&RK2[rkb];
        int4 r1 = *(const int4*)&RK2[rkb + 4];
        if (r0.x >= 0) ob[r0.x] = ve[0];
        if (r0.y >= 0) ob[r0.y] = ve[1];
        if (r0.z >= 0) ob[r0.z] = ve[2];
        if (r0.w >= 0) ob[r0.w] = ve[3];
        if (r1.x >= 0) ob[r1.x] = ve[4];
        if (r1.y >= 0) ob[r1.y] = ve[5];
        if (r1.z >= 0) ob[r1.z] = ve[6];
        if (r1.w >= 0) ob[r1.w] = ve[7];
    }
}

extern "C" void kernel_launch(void* const* d_in, const int* in_sizes, int n_in,
                              void* d_out, int out_size, void* d_ws, size_t ws_size,
                              hipStream_t stream) {
    const float* rx   = (const float*)d_in[0];
    const int*   info = (const int*)d_in[1];
    float*       outp = (float*)d_out;
    polar_bp_r15<<<dim3(BATCH / 2), dim3(256), 0, stream>>>(rx, info, outp);
}

// Round 16
// 32.201 us; speedup vs baseline: 1.2537x; 1.1045x over previous
//
#include <hip/hip_runtime.h>

constexpr int CODE_LEN = 1024;
constexpr int INFO_LEN = 512;
constexpr int BATCH    = 2048;
constexpr int ITERS    = 5;
#define CLIPV 15.0f

// f(a,b) = sign(a)*sign(b)*min(|a|,|b|) -- forced 3-inst codegen.
__device__ __forceinline__ float fop(float a, float b) {
    unsigned x; float m, r;
    asm("v_xor_b32 %0, %1, %2" : "=v"(x) : "v"(a), "v"(b));
    asm("v_min_f32 %0, |%1|, |%2|" : "=v"(m) : "v"(a), "v"(b));
    asm("v_and_or_b32 %0, %1, %2, %3" : "=v"(r) : "v"(x), "s"(0x80000000u), "v"(m));
    return r;
}
// clip = single v_med3_f32
__device__ __forceinline__ float clipf(float x) {
    return __builtin_amdgcn_fmed3f(x, -CLIPV, CLIPV);
}

// ---------------------------------------------------------------------------
// FINAL (== R9, the empirical optimum after the R10-R15 sweep):
// 4 slots/thread, 4 waves/codeword, layout-group scheme: position p lives at
// (wave,lane,slot); every butterfly stage is select-free between register
// slots; group transitions convert ONE boundary array via LDS (CONV_W
// in-wave, no barrier; CONV_X cross-wave, 1 barrier), sigma-swizzled to
// near-conflict-free. asm-tight fop (3 VALU), redundant clips dropped
// (u-outputs with already-clipped min-arg), iteration-0 right pass peeled
// (left arrays all zero). 48 VGPR -> 8 waves/SIMD; grid = 2048 blocks.
// Probed and rejected: in-reg DPP/permlane conversions (R13/R14: DPP chains
// + hazard waits cost more than LDS), ILP-2 (R11), 8-slot/fewer-barriers
// (R15: occupancy halves), bank-conflict/read-merge micro-opts (R10: null).
// ---------------------------------------------------------------------------

#define RSTEP0(A, B) do { \
    float bu0=(B)[0], bl0=(B)[1], bu1=(B)[2], bl1=(B)[3]; \
    (B)[0]=fop((A)[0], bl0+(A)[1]); \
    (B)[1]=clipf(fop((A)[0], bu0)+(A)[1]); \
    (B)[2]=fop((A)[2], bl1+(A)[3]); \
    (B)[3]=clipf(fop((A)[2], bu1)+(A)[3]); } while(0)
#define RSTEP1(A, B) do { \
    float bu0=(B)[0], bl0=(B)[2], bu1=(B)[1], bl1=(B)[3]; \
    (B)[0]=fop((A)[0], bl0+(A)[2]); \
    (B)[2]=clipf(fop((A)[0], bu0)+(A)[2]); \
    (B)[1]=fop((A)[1], bl1+(A)[3]); \
    (B)[3]=clipf(fop((A)[1], bu1)+(A)[3]); } while(0)
#define LSTEP0(A, B) do { \
    float au0=(A)[0], al0=(A)[1], au1=(A)[2], al1=(A)[3]; \
    (A)[0]=fop((B)[0], (B)[1]+al0); \
    (A)[1]=clipf(fop(au0, (B)[0])+(B)[1]); \
    (A)[2]=fop((B)[2], (B)[3]+al1); \
    (A)[3]=clipf(fop(au1, (B)[2])+(B)[3]); } while(0)
#define LSTEP1(A, B) do { \
    float au0=(A)[0], al0=(A)[2], au1=(A)[1], al1=(A)[3]; \
    (A)[0]=fop((B)[0], (B)[2]+al0); \
    (A)[2]=clipf(fop(au0, (B)[0])+(B)[2]); \
    (A)[1]=fop((B)[1], (B)[3]+al1); \
    (A)[3]=clipf(fop(au1, (B)[1])+(B)[3]); } while(0)
// stage-9 left step: B = rx (UNclipped) -> keep u-clip
#define LSTEP1C(A, B) do { \
    float au0=(A)[0], al0=(A)[2], au1=(A)[1], al1=(A)[3]; \
    (A)[0]=clipf(fop((B)[0], (B)[2]+al0)); \
    (A)[2]=clipf(fop(au0, (B)[0])+(B)[2]); \
    (A)[1]=clipf(fop((B)[1], (B)[3]+al1)); \
    (A)[3]=clipf(fop(au1, (B)[1])+(B)[3]); } while(0)
// iteration-0 right steps (l == 0): u' = fop(r_u, r_l), l' = r_l
#define RSTEP0Z(A, B) do { \
    (B)[0]=fop((A)[0], (A)[1]); (B)[1]=(A)[1]; \
    (B)[2]=fop((A)[2], (A)[3]); (B)[3]=(A)[3]; } while(0)
#define RSTEP1Z(A, B) do { \
    (B)[0]=fop((A)[0], (A)[2]); (B)[2]=(A)[2]; \
    (B)[1]=fop((A)[1], (A)[3]); (B)[3]=(A)[3]; } while(0)

#define CONV_W(arr, R) do { \
    *(float4*)&WB[offW] = make_float4((arr)[0], (arr)[1], (arr)[2], (arr)[3]); \
    float c0_ = WB[(R)[0]], c1_ = WB[(R)[1]], c2_ = WB[(R)[2]], c3_ = WB[(R)[3]]; \
    (arr)[0]=c0_; (arr)[1]=c1_; (arr)[2]=c2_; (arr)[3]=c3_; } while(0)

#define CONV_X(arr, XBUF) do { \
    *(float4*)&(XBUF)[offXw] = make_float4((arr)[0], (arr)[1], (arr)[2], (arr)[3]); \
    __syncthreads(); \
    (arr)[0]=(XBUF)[offXr];     (arr)[1]=(XBUF)[offXr+256]; \
    (arr)[2]=(XBUF)[offXr+512]; (arr)[3]=(XBUF)[offXr+768]; } while(0)

__global__ __launch_bounds__(256, 4) void polar_bp_fin(const float* __restrict__ rx,
                                                       const int* __restrict__ info,
                                                       float* __restrict__ out) {
    __shared__ int   RK[CODE_LEN];    // rank table in L0 flat order (init only)
    __shared__ float WB[CODE_LEN];    // per-wave conversion scratch (4x256)
    __shared__ float XB0[CODE_LEN];   // cross-wave buffers
    __shared__ float XB1[CODE_LEN];

    const int t = threadIdx.x;
    const int b = blockIdx.x;

    // RK[L0-flat] = rank or -1. flat(p) = p10 | p76<<2 | p54<<4 | p32<<6 | p98<<8
    *(int4*)&RK[t * 4] = make_int4(-1, -1, -1, -1);
    __syncthreads();
#pragma unroll
    for (int k = 0; k < 2; ++k) {
        int kk = t + 256 * k;
        int p  = info[kk];
        int fl = (p & 3) | (((p >> 6) & 3) << 2) | (((p >> 4) & 3) << 4)
               | (((p >> 2) & 3) << 6) | (((p >> 8) & 3) << 8);
        RK[fl] = kk;
    }
    __syncthreads();

    // ---- precomputed LDS word offsets (iteration-invariant) ----
    const int l6 = t & 63;
    const int wbase = (t >> 6) * 256;
    const int offW  = wbase + 4 * (l6 ^ (l6 >> 2));   // sigma-swizzled write
    int offR4[4], offR2[4], offR0[4];
#pragma unroll
    for (int k = 0; k < 4; ++k) {
        int g4 = (l6 & ~(3 << 4)) | (k << 4);
        int g2 = (l6 & ~(3 << 2)) | (k << 2);
        int g0 = (l6 & ~3) | k;
        offR4[k] = wbase + 4 * (g4 ^ (g4 >> 2)) + ((l6 >> 4) & 3);
        offR2[k] = wbase + 4 * (g2 ^ (g2 >> 2)) + ((l6 >> 2) & 3);
        offR0[k] = wbase + 4 * (g0 ^ (g0 >> 2)) + (l6 & 3);
    }
    const int offXw = t * 4;
    const int offXr = (t & 63) * 4 + (t >> 6);

    // ---- per-thread constants: ranks + frozen vector ----
    const int4 rkv = *(const int4*)&RK[t * 4];
    float fr[4];
    fr[0] = rkv.x < 0 ? CLIPV : 0.f;  fr[1] = rkv.y < 0 ? CLIPV : 0.f;
    fr[2] = rkv.z < 0 ? CLIPV : 0.f;  fr[3] = rkv.w < 0 ? CLIPV : 0.f;

    float S[10][4];
    // rx -> S[9] in L4 order: p = e*256 + t76*64 + t10*16 + t32*4 + t54
    {
        const float* rxb = rx + (size_t)b * CODE_LEN
                         + ((t >> 6) & 3) * 64 + (t & 3) * 16
                         + ((t >> 2) & 3) * 4 + ((t >> 4) & 3);
        S[9][0] = rxb[0];   S[9][1] = rxb[256];
        S[9][2] = rxb[512]; S[9][3] = rxb[768];
    }

    // ===== iteration-0 RIGHT pass, peeled: all left arrays are zero =====
    RSTEP0Z(fr, S[0]);
    RSTEP1Z(S[0], S[1]);
    CONV_W(S[1], offR4);       // C01  L0->L1
    RSTEP0Z(S[1], S[2]);
    RSTEP1Z(S[2], S[3]);
    CONV_W(S[3], offR2);       // C12  L1->L2
    RSTEP0Z(S[3], S[4]);
    RSTEP1Z(S[4], S[5]);
    CONV_W(S[5], offR0);       // C23  L2->L3
    RSTEP0Z(S[5], S[6]);
    RSTEP1Z(S[6], S[7]);
    CONV_X(S[7], XB0);         // C34  L3->L4 (barrier)
    RSTEP0Z(S[7], S[8]);       // s8 (right stage 9 output unused)

    float v0, v1, v2, v3;
    float* ob = out + (size_t)b * INFO_LEN;
    const size_t obstride = (size_t)BATCH * INFO_LEN;

#pragma unroll 1
    for (int it = 0; it < ITERS; ++it) {
        // ===================== LEFT pass (s = 9..0) ======================
        LSTEP1C(S[8], S[9]);       // s9: l = rx (unclipped) -> keep u-clip
        LSTEP0(S[7], S[8]);        // s8
        CONV_X(S[7], XB1);         // C43  L4->L3 (barrier)
        LSTEP1(S[6], S[7]);        // s7
        LSTEP0(S[5], S[6]);        // s6
        CONV_W(S[5], offR0);       // C32  L3->L2
        LSTEP1(S[4], S[5]);        // s5
        LSTEP0(S[3], S[4]);        // s4
        CONV_W(S[3], offR2);       // C21  L2->L1
        LSTEP1(S[2], S[3]);        // s3
        LSTEP0(S[1], S[2]);        // s2
        CONV_W(S[1], offR4);       // C10  L1->L0
        LSTEP1(S[0], S[1]);        // s1 -> S[0] = left[1]
        // s0: emit left[0] at info positions (right[0] = 0 there), L0 order
        v0 = fop(S[0][0], S[0][1] + fr[1]);
        v1 = clipf(fop(fr[0], S[0][0]) + S[0][1]);
        v2 = fop(S[0][2], S[0][3] + fr[3]);
        v3 = clipf(fop(fr[2], S[0][2]) + S[0][3]);
        if (rkv.x >= 0) ob[rkv.x] = v0;
        if (rkv.y >= 0) ob[rkv.y] = v1;
        if (rkv.z >= 0) ob[rkv.z] = v2;
        if (rkv.w >= 0) ob[rkv.w] = v3;
        ob += obstride;
        // ===================== RIGHT pass (s = 0..8) =====================
        if (it != ITERS - 1) {
            RSTEP0(fr, S[0]);
            RSTEP1(S[0], S[1]);
            CONV_W(S[1], offR4);       // C01
            RSTEP0(S[1], S[2]);
            RSTEP1(S[2], S[3]);
            CONV_W(S[3], offR2);       // C12
            RSTEP0(S[3], S[4]);
            RSTEP1(S[4], S[5]);
            CONV_W(S[5], offR0);       // C23
            RSTEP0(S[5], S[6]);
            RSTEP1(S[6], S[7]);
            CONV_X(S[7], XB0);         // C34 (barrier)
            RSTEP0(S[7], S[8]);
        }
    }
    // duplicate row: out[ITERS] = out[ITERS-1]
    if (rkv.x >= 0) ob[rkv.x] = v0;
    if (rkv.y >= 0) ob[rkv.y] = v1;
    if (rkv.z >= 0) ob[rkv.z] = v2;
    if (rkv.w >= 0) ob[rkv.w] = v3;
}

extern "C" void kernel_launch(void* const* d_in, const int* in_sizes, int n_in,
                              void* d_out, int out_size, void* d_ws, size_t ws_size,
                              hipStream_t stream) {
    const float* rx   = (const float*)d_in[0];
    const int*   info = (const int*)d_in[1];
    float*       outp = (float*)d_out;
    polar_bp_fin<<<dim3(BATCH), dim3(256), 0, stream>>>(rx, info, outp);
}